// Round 5
// baseline (238.532 us; speedup 1.0000x reference)
//
#include <hip/hip_runtime.h>
#include <hip/hip_fp16.h>

// out[row] = sum_edges(0.4*val * x[col]) - x[row] + e[row]
//
// Two-level binning to kill the scatter-transaction bottleneck:
//  prep:   x -> fp16 shadow convert (dense BW) + coarse-bin edges into
//          3125 buckets of 32 rows (row>>5). Atomic counters: 12.5KB hot.
//          Payload append streams are dense lines (no 100k-line scatter).
//          Entry = 8B packed u64: {col | (row&31)<<17 , f32 0.4*val}.
//  gather: one block per bucket. Stage entries in LDS, counting-sort into
//          a per-row CSR in LDS (LDS atomics + wave scan), then 32-lane/row
//          fp16 gather with 8-deep MLP, fused -x + e epilogue (NT streams).
// Coarse overflow (P ~ 1e-12) -> tiny global list scanned when nonzero.

#define EMB_DIM 128
#define Q_SLOTS 32            // EMB_DIM/4 float4 slots per row
#define RPB 32                // rows per coarse bucket (row >> 5)
#define CAP_C 384             // entries per bucket; mean 200, +13 sigma
#define OVF_MAX 8192

struct __align__(8) half4_t { __half2 a, b; };   // 4 halfs = 8B
typedef float f32x4 __attribute__((ext_vector_type(4)));
typedef unsigned long long u64;

// ---- Prep: fp16 shadow of x + coarse binning ----
__global__ void prep_kernel(const int* __restrict__ rows,
                            const int* __restrict__ cols,
                            const float* __restrict__ vals,
                            int* __restrict__ ccnt,
                            u64* __restrict__ coarse,
                            int* __restrict__ ovf_cursor,
                            int4* __restrict__ ovf,
                            int n_edges,
                            const f32x4* __restrict__ x4,
                            half4_t* __restrict__ xh4,
                            int n_x4) {
    int i = blockIdx.x * blockDim.x + threadIdx.x;
    if (i < n_x4) {
        f32x4 f = __builtin_nontemporal_load(x4 + i);   // x read once: NT
        half4_t h;
        h.a = __floats2half2_rn(f.x, f.y);
        h.b = __floats2half2_rn(f.z, f.w);
        xh4[i] = h;                                     // reused next kernel
    }
    if (i < n_edges) {
        int   r  = __builtin_nontemporal_load(rows + i);
        int   c  = __builtin_nontemporal_load(cols + i);
        float vv = __builtin_nontemporal_load(vals + i);
        int b = r >> 5;
        int pos = atomicAdd(&ccnt[b], 1);
        unsigned lo = (unsigned)(c | ((r & (RPB - 1)) << 17));
        unsigned hi = (unsigned)__float_as_int(0.4f * vv);
        u64 pv = (u64)lo | ((u64)hi << 32);
        if (pos < CAP_C) {
            __builtin_nontemporal_store(pv, coarse + (size_t)b * CAP_C + pos);
        } else {
            int o = atomicAdd(ovf_cursor, 1);
            if (o < OVF_MAX) ovf[o] = make_int4(r, c, __float_as_int(0.4f * vv), 0);
        }
    }
}

// ---- Fused fine-bin + gather: one block per 32-row bucket ----
__global__ void __launch_bounds__(256, 8)
bin_gather_kernel(const half4_t* __restrict__ xh4,
                  const f32x4* __restrict__ e4,
                  const int* __restrict__ ccnt,
                  const u64* __restrict__ coarse,
                  const int* __restrict__ ovf_cursor,
                  const int4* __restrict__ ovf,
                  f32x4* __restrict__ out4, int n_nodes) {
    __shared__ int  s_cnt[RPB];
    __shared__ int  s_off[RPB + 1];
    __shared__ int  s_cur[RPB];
    __shared__ int2 s_raw[CAP_C];
    __shared__ int2 s_ent[CAP_C];
    __shared__ int  s_ovf;

    int b = blockIdx.x;
    int t = threadIdx.x;
    int row_base = b * RPB;

    int nb = ccnt[b];                       // uniform load
    nb = (nb < CAP_C) ? nb : CAP_C;

    if (t < RPB) s_cnt[t] = 0;
    if (t == 0) s_ovf = *ovf_cursor;
    __syncthreads();

    const u64* cb = coarse + (size_t)b * CAP_C;
    // stage + count
    for (int j = t; j < nb; j += 256) {
        u64 pv = __builtin_nontemporal_load(cb + j);    // read exactly once
        int lo = (int)(pv & 0xffffffffULL);
        int hi = (int)(pv >> 32);
        s_raw[j] = make_int2(lo, hi);
        atomicAdd(&s_cnt[(lo >> 17) & (RPB - 1)], 1);
    }
    __syncthreads();
    // exclusive offsets via wave scan (first wave)
    if (t < 64) {
        int v = (t < RPB) ? s_cnt[t] : 0;
        int incl = v;
#pragma unroll
        for (int d = 1; d < RPB; d <<= 1) {
            int o = __shfl_up(incl, d, 64);
            if ((t & 63) >= d) incl += o;
        }
        if (t < RPB) { s_off[t + 1] = incl; s_cur[t] = incl - v; }
        if (t == 0) s_off[0] = 0;
    }
    __syncthreads();
    // place into CSR order
    for (int j = t; j < nb; j += 256) {
        int2 en = s_raw[j];
        int r = (en.x >> 17) & (RPB - 1);
        int pos = atomicAdd(&s_cur[r], 1);
        s_ent[pos] = make_int2(en.x & 0x1FFFF, en.y);
    }
    __syncthreads();

    // gather: 8 teams x 32 lanes; 4 rows per team
    int team = t >> 5;
    int q    = t & 31;
    int ocnt = s_ovf;
    ocnt = (ocnt < OVF_MAX) ? ocnt : OVF_MAX;

    for (int rr = team; rr < RPB; rr += 8) {
        int grow = row_base + rr;
        if (grow >= n_nodes) continue;
        int start = s_off[rr], end = s_off[rr + 1];

        float4 acc = make_float4(0.f, 0.f, 0.f, 0.f);
        for (int jb = start; jb < end; jb += 8) {
            int   col[8];
            float v[8];
#pragma unroll
            for (int k = 0; k < 8; ++k) {
                int j  = jb + k;
                int jc = (j < end) ? j : end - 1;       // clamp: dup L1 hit, v=0
                int2 en = s_ent[jc];                    // LDS broadcast
                col[k] = en.x;
                v[k]   = (j < end) ? __int_as_float(en.y) : 0.f;
            }
            half4_t hv[8];
#pragma unroll
            for (int k = 0; k < 8; ++k) {
                hv[k] = xh4[col[k] * Q_SLOTS + q];
            }
#pragma unroll
            for (int k = 0; k < 8; ++k) {
                float2 f0 = __half22float2(hv[k].a);
                float2 f1 = __half22float2(hv[k].b);
                acc.x = fmaf(v[k], f0.x, acc.x);
                acc.y = fmaf(v[k], f0.y, acc.y);
                acc.z = fmaf(v[k], f1.x, acc.z);
                acc.w = fmaf(v[k], f1.y, acc.w);
            }
        }

        // rare: coarse-bucket overflow entries for this row
        if (ocnt > 0) {
            for (int k = 0; k < ocnt; ++k) {
                int4 en = ovf[k];
                if (en.x == grow) {
                    float vv = __int_as_float(en.z);
                    half4_t hv = xh4[en.y * Q_SLOTS + q];
                    float2 f0 = __half22float2(hv.a);
                    float2 f1 = __half22float2(hv.b);
                    acc.x = fmaf(vv, f0.x, acc.x);
                    acc.y = fmaf(vv, f0.y, acc.y);
                    acc.z = fmaf(vv, f1.x, acc.z);
                    acc.w = fmaf(vv, f1.y, acc.w);
                }
            }
        }

        int idx = grow * Q_SLOTS + q;
        half4_t hx = xh4[idx];                           // epilogue x (fp16)
        float2 x0 = __half22float2(hx.a);
        float2 x1 = __half22float2(hx.b);
        f32x4 er = __builtin_nontemporal_load(e4 + idx); // e: pure stream
        f32x4 o;
        o.x = acc.x + er.x - x0.x;
        o.y = acc.y + er.y - x0.y;
        o.z = acc.z + er.z - x1.x;
        o.w = acc.w + er.w - x1.y;
        __builtin_nontemporal_store(o, out4 + idx);      // out: pure stream
    }
}

// ---- Fallback (ws too small or n_nodes too large for packing): chains ----
__global__ void build_chain_kernel(const int* __restrict__ rows,
                                   const int* __restrict__ cols,
                                   const float* __restrict__ vals,
                                   int* __restrict__ head,
                                   int4* __restrict__ nodes, int n_edges) {
    int i = blockIdx.x * blockDim.x + threadIdx.x;
    if (i >= n_edges) return;
    int r = rows[i];
    int prev = atomicExch(&head[r], i);
    nodes[i] = make_int4(cols[i], __float_as_int(0.4f * vals[i]), prev, 0);
}
__global__ void gather_chain_kernel(const float2* __restrict__ x2,
                                    const float2* __restrict__ e2,
                                    const int* __restrict__ head,
                                    const int4* __restrict__ nodes,
                                    float2* __restrict__ out2, int n_nodes) {
    int tid = blockIdx.x * blockDim.x + threadIdx.x;
    int row = tid >> 6, q = tid & 63;
    if (row >= n_nodes) return;
    float2 acc = make_float2(0.f, 0.f);
    int j = head[row];
    if (j >= 0) {
        int4 nd = nodes[j];
        for (;;) {
            int4 nd2;
            bool more = (nd.z >= 0);
            if (more) nd2 = nodes[nd.z];
            float v = __int_as_float(nd.y);
            float2 xv = x2[nd.x * 64 + q];
            acc.x = fmaf(v, xv.x, acc.x);
            acc.y = fmaf(v, xv.y, acc.y);
            if (!more) break;
            nd = nd2;
        }
    }
    int idx = row * 64 + q;
    float2 xr = x2[idx], er = e2[idx];
    out2[idx] = make_float2(acc.x + er.x - xr.x, acc.y + er.y - xr.y);
}

extern "C" void kernel_launch(void* const* d_in, const int* in_sizes, int n_in,
                              void* d_out, int out_size, void* d_ws, size_t ws_size,
                              hipStream_t stream) {
    // Inputs: t, x, e, hg_vals, hg_rows, hg_cols
    const float* x    = (const float*)d_in[1];
    const float* e    = (const float*)d_in[2];
    const float* vals = (const float*)d_in[3];
    const int*   rows = (const int*)d_in[4];
    const int*   cols = (const int*)d_in[5];
    float* out = (float*)d_out;

    const int n_edges = in_sizes[3];
    const int n_nodes = in_sizes[1] / EMB_DIM;
    const int n_x4    = n_nodes * Q_SLOTS;             // float4 slots in x
    const int n_buck  = (n_nodes + RPB - 1) / RPB;

    // Tier A: ovf | xh shadow | coarse | ccnt | cursor
    size_t need_a = (size_t)OVF_MAX * sizeof(int4) +
                    (size_t)n_x4 * sizeof(half4_t) +
                    (size_t)n_buck * CAP_C * sizeof(u64) +
                    (size_t)(n_buck + 1) * sizeof(int);

    if (ws_size >= need_a && n_nodes <= (1 << 17)) {
        int4*    ovf        = (int4*)d_ws;
        half4_t* xh4        = (half4_t*)(ovf + OVF_MAX);
        u64*     coarse     = (u64*)(xh4 + (size_t)n_x4);
        int*     ccnt       = (int*)(coarse + (size_t)n_buck * CAP_C);
        int*     ovf_cursor = ccnt + n_buck;

        hipMemsetAsync(ccnt, 0, (size_t)(n_buck + 1) * sizeof(int), stream);

        int pt = (n_x4 > n_edges) ? n_x4 : n_edges;
        int pb = (pt + 255) / 256;
        prep_kernel<<<pb, 256, 0, stream>>>(rows, cols, vals, ccnt, coarse,
                                            ovf_cursor, ovf, n_edges,
                                            (const f32x4*)x, xh4, n_x4);

        bin_gather_kernel<<<n_buck, 256, 0, stream>>>(xh4, (const f32x4*)e,
                                                      ccnt, coarse,
                                                      ovf_cursor, ovf,
                                                      (f32x4*)out, n_nodes);
    } else {
        // Fallback: chain approach
        int4* nodes = (int4*)d_ws;
        int*  head  = (int*)(nodes + n_edges);
        hipMemsetAsync(head, 0xFF, (size_t)n_nodes * sizeof(int), stream);
        int eb = (n_edges + 255) / 256;
        build_chain_kernel<<<eb, 256, 0, stream>>>(rows, cols, vals, head,
                                                   nodes, n_edges);
        long long gt = (long long)n_nodes * 64;
        int gb = (int)((gt + 255) / 256);
        gather_chain_kernel<<<gb, 256, 0, stream>>>((const float2*)x,
                                                    (const float2*)e,
                                                    head, nodes,
                                                    (float2*)out, n_nodes);
    }
}